// Round 12
// baseline (232.069 us; speedup 1.0000x reference)
//
#include <hip/hip_runtime.h>

// R16: REGISTER-RESIDENT gauss chain. Key identity (derived from the proven
// R14 fragment layouts): with 16x16x16 MFMAs and the A=xp^T / B=K~ operand
// convention, each stage's D-output (after per-lane f32->f16 cvt) IS the next
// stage's A/B fragment — no LDS round-trips, no DS fences, no in-place hazard.
//   stage_b out tile: lane(lo,hi)=act[nt16+lo][ot16+hi4+q] == stage_a A(mt=nt,kc=ot)
//   stage_a out tile: lane(lo,hi)=xp[mt16+hi4+q][nt16+lo]  == stage_b A(kc=mt,ot=nt)
// LDS only stages final h (same swizzled f16x4 write as R14) for the proven
// fused dense phase. 16 waves/block, 1 sample/wave, 128KB LDS, 4 generations.

typedef _Float16 f16x8 __attribute__((ext_vector_type(8)));
typedef _Float16 f16x4 __attribute__((ext_vector_type(4)));
typedef __fp16   hf2   __attribute__((ext_vector_type(2)));   // cvt_pkrtz result type
typedef float    f32x4 __attribute__((ext_vector_type(4)));

// ws layout (halves): wm0 tiled [128][80][32]; K~ [4][64][64]; padded weights
#define KT_OFF    327680
#define W0P_OFF   344064               // [16][64], rows>=8 zero
#define W1P_OFF   345088               // [16][16], cols>=8 zero
#define W2P_OFF   345344               // [32][16], all valid
#define W3P_OFF   345856               // [64][32]

__global__ void prep_all(const float* __restrict__ s0, const float* __restrict__ s1,
                         const float* __restrict__ s2, const float* __restrict__ s3,
                         const float* __restrict__ w0, const float* __restrict__ w1,
                         const float* __restrict__ w2, const float* __restrict__ w3,
                         const float* __restrict__ wm0, _Float16* __restrict__ base) {
  int bid = blockIdx.x, tid = threadIdx.x;
  if (bid < 1280) {
    // wm0 fp32 [80][4096] -> fp16 tiled [kc][n][32]
    int idx = bid * 256 + tid;
    int kc = idx / 2560, rem = idx % 2560;
    int n = rem >> 5, o = rem & 31;
    base[idx] = (_Float16)wm0[n * 4096 + kc * 32 + o];
  } else if (bid == 1280) {
    // K~ : L1-normalized gaussian rows, fp16 [4][64][64]
    int li = tid >> 6, i = tid & 63;
    float sg = (li == 0) ? s0[0] : (li == 1) ? s1[0] : (li == 2) ? s2[0] : s3[0];
    float denom = 2.0f * sg * sg;
    float sum = 0.0f;
    for (int j = 0; j < 64; ++j) {
      float d = (float)(i - j);
      sum += expf(-(d * d) / denom);
    }
    float inv = 1.0f / fmaxf(sum, 1e-12f);
    for (int j = 0; j < 64; ++j) {
      float d = (float)(i - j);
      base[KT_OFF + (li * 64 + i) * 64 + j] = (_Float16)(expf(-(d * d) / denom) * inv);
    }
  } else {
    // small layer weights, zero-padded to MFMA tiles (3840 halves total)
    for (int r = tid; r < 3840; r += 256) {
      float v;
      if (r < 1024)      { int o = r >> 6, c = r & 63;             v = (o < 8) ? w0[o * 64 + c] : 0.0f; }
      else if (r < 1280) { int q = r - 1024; int o = q >> 4, c = q & 15; v = (c < 8) ? w1[o * 8 + c] : 0.0f; }
      else if (r < 1792) { int q = r - 1280; int o = q >> 4, c = q & 15; v = w2[o * 16 + c]; }
      else               { int q = r - 1792; int o = q >> 5, c = q & 31; v = w3[o * 32 + c]; }
      base[W0P_OFF + r] = (_Float16)v;
    }
  }
}

__device__ __forceinline__ float leaky(float v) { return v > 0.0f ? v : 0.01f * v; }

// packed f32x4 -> f16x4 via v_cvt_pkrtz
__device__ __forceinline__ f16x4 pk4(float a, float b, float c, float d) {
  union { f16x4 v; hf2 p[2]; } u;
  u.p[0] = __builtin_amdgcn_cvt_pkrtz(a, b);
  u.p[1] = __builtin_amdgcn_cvt_pkrtz(c, d);
  return u.v;
}

// swizzled offset (halves) in an 8KB 64x64 fp16 buffer: 16B chunk j -> j ^ (row&7) ^ sx
__device__ __forceinline__ int swz(int sx, int row, int c) {
  return row * 64 + ((((c >> 3) ^ (row & 7) ^ sx) & 7) << 3) + (c & 7);
}

__device__ __forceinline__ f16x8 ldf(const _Float16* p) { return *(const f16x8*)p; }
__device__ __forceinline__ f16x4 ldf4(const _Float16* p) { return *(const f16x4*)p; }

#define MFMA16(A, B, C) __builtin_amdgcn_mfma_f32_16x16x16f16((A), (B), (C), 0, 0, 0)
#define MFMA32(A, B, C) __builtin_amdgcn_mfma_f32_16x16x32_f16((A), (B), (C), 0, 0, 0)

__global__ __launch_bounds__(1024, 4)
void fused(const float* __restrict__ x,
           const float* __restrict__ bb0, const float* __restrict__ bb1,
           const float* __restrict__ bb2, const float* __restrict__ bb3,
           const _Float16* __restrict__ wsh,
           const float* __restrict__ bm0, const float* __restrict__ wm1,
           const float* __restrict__ bm1, float* __restrict__ out, int B) {
  __shared__ _Float16 lds[16][4096];  // 128KB: 16 samples x (64x64 fp16), h staging
  const int tid = threadIdx.x;
  const int wv = tid >> 6, lane = tid & 63;
  const int lo = lane & 15, hi = lane >> 4;
  const int smp0 = blockIdx.x * 16;
  int smp = smp0 + wv;  if (smp >= B) smp = B - 1;   // clamp; masked at final store
  _Float16* P = lds[wv];
  const int sx = wv;
  const _Float16* kt = wsh + KT_OFF;

  float bv0 = (lo < 8) ? bb0[lo] : 0.0f;
  float bv1 = bb1[lo];
  float bv2[2] = {bb2[lo], bb2[16 + lo]};
  float bv3[4] = {bb3[lo], bb3[16 + lo], bb3[32 + lo], bb3[48 + lo]};

  // ---- L0a: xp0 = x @ w0^T  (A from global fp32 x, K=32 MFMAs, bias in C) ----
  const float* xr = x + (size_t)smp * 4096;
  f16x8 wf0[2];
#pragma unroll
  for (int kc = 0; kc < 2; ++kc)
    wf0[kc] = ldf(wsh + W0P_OFF + lo * 64 + kc * 32 + hi * 8);
  f16x4 xp0[4];                       // lane = xp0[mt*16+hi*4+q][lo]
#pragma unroll
  for (int mt = 0; mt < 4; ++mt) {
    f32x4 acc = {bv0, bv0, bv0, bv0};
#pragma unroll
    for (int kc = 0; kc < 2; ++kc) {
      const float4* p4 = (const float4*)(xr + (mt * 16 + lo) * 64 + kc * 32 + hi * 8);
      float4 v0 = p4[0], v1 = p4[1];
      union { f16x8 v; hf2 p[4]; } u;
      u.p[0] = __builtin_amdgcn_cvt_pkrtz(v0.x, v0.y);
      u.p[1] = __builtin_amdgcn_cvt_pkrtz(v0.z, v0.w);
      u.p[2] = __builtin_amdgcn_cvt_pkrtz(v1.x, v1.y);
      u.p[3] = __builtin_amdgcn_cvt_pkrtz(v1.z, v1.w);
      acc = MFMA32(u.v, wf0[kc], acc);
    }
    xp0[mt] = pk4(acc[0], acc[1], acc[2], acc[3]);    // no activation on xp
  }
  // note: xp0 cols(lo)>=8 are exactly 0 (bv0 pad=0, W0P rows>=8 zero)

  // ---- L0b: a1 = leaky(K~0 @ xp0)  ( A = xp0^T frags = xp0[] directly ) ----
  f16x4 kb[4][4];                     // K~[nt*16+lo][kc*16+hi*4+j]
#pragma unroll
  for (int nt = 0; nt < 4; ++nt)
#pragma unroll
    for (int kc = 0; kc < 4; ++kc)
      kb[nt][kc] = ldf4(kt + 0 * 4096 + (nt * 16 + lo) * 64 + kc * 16 + hi * 4);
  f16x4 a1[4];                        // lane = a1[nt*16+lo][hi*4+q]
#pragma unroll
  for (int nt = 0; nt < 4; ++nt) {
    f32x4 acc = {0.0f, 0.0f, 0.0f, 0.0f};
#pragma unroll
    for (int kc = 0; kc < 4; ++kc)
      acc = MFMA16(xp0[kc], kb[nt][kc], acc);
    a1[nt] = pk4(leaky(acc[0]), leaky(acc[1]), leaky(acc[2]), leaky(acc[3]));
  }

  // ---- L1a: xp1 = a1 @ w1^T  (A = a1[] directly) ----
  f16x4 wf1 = ldf4(wsh + W1P_OFF + lo * 16 + hi * 4);
  f16x4 xp1[4];
#pragma unroll
  for (int mt = 0; mt < 4; ++mt) {
    f32x4 acc = {bv1, bv1, bv1, bv1};
    acc = MFMA16(a1[mt], wf1, acc);
    xp1[mt] = pk4(acc[0], acc[1], acc[2], acc[3]);
  }

  // ---- L1b: a2 = leaky(K~1 @ xp1) ----
#pragma unroll
  for (int nt = 0; nt < 4; ++nt)
#pragma unroll
    for (int kc = 0; kc < 4; ++kc)
      kb[nt][kc] = ldf4(kt + 1 * 4096 + (nt * 16 + lo) * 64 + kc * 16 + hi * 4);
  f16x4 a2[4];
#pragma unroll
  for (int nt = 0; nt < 4; ++nt) {
    f32x4 acc = {0.0f, 0.0f, 0.0f, 0.0f};
#pragma unroll
    for (int kc = 0; kc < 4; ++kc)
      acc = MFMA16(xp1[kc], kb[nt][kc], acc);
    a2[nt] = pk4(leaky(acc[0]), leaky(acc[1]), leaky(acc[2]), leaky(acc[3]));
  }

  // ---- L2a: xp2 = a2 @ w2^T  (C'=32 -> 2 nt) ----
  f16x4 wf2[2];
#pragma unroll
  for (int nt = 0; nt < 2; ++nt)
    wf2[nt] = ldf4(wsh + W2P_OFF + (nt * 16 + lo) * 16 + hi * 4);
  f16x4 xp2[4][2];                    // [mt][nt], lane = xp2[mt16+hi4+q][nt16+lo]
#pragma unroll
  for (int mt = 0; mt < 4; ++mt)
#pragma unroll
    for (int nt = 0; nt < 2; ++nt) {
      f32x4 acc = {bv2[nt], bv2[nt], bv2[nt], bv2[nt]};
      acc = MFMA16(a2[mt], wf2[nt], acc);
      xp2[mt][nt] = pk4(acc[0], acc[1], acc[2], acc[3]);
    }

  // ---- L2b: a3 = leaky(K~2 @ xp2) ----
#pragma unroll
  for (int nt = 0; nt < 4; ++nt)
#pragma unroll
    for (int kc = 0; kc < 4; ++kc)
      kb[nt][kc] = ldf4(kt + 2 * 4096 + (nt * 16 + lo) * 64 + kc * 16 + hi * 4);
  f16x4 a3[4][2];                     // [ct=i'][rt=o'], lane = a3[ct16+lo][rt16+hi4+q]
#pragma unroll
  for (int ct = 0; ct < 4; ++ct)
#pragma unroll
    for (int rt = 0; rt < 2; ++rt) {
      f32x4 acc = {0.0f, 0.0f, 0.0f, 0.0f};
#pragma unroll
      for (int kc = 0; kc < 4; ++kc)
        acc = MFMA16(xp2[kc][rt], kb[ct][kc], acc);
      a3[ct][rt] = pk4(leaky(acc[0]), leaky(acc[1]), leaky(acc[2]), leaky(acc[3]));
    }

  // ---- L3a: xp3 = a3 @ w3^T  (K=32 -> 2 kc, C'=64 -> 4 nt) ----
  f16x4 wf3[4][2];
#pragma unroll
  for (int nt = 0; nt < 4; ++nt)
#pragma unroll
    for (int kc = 0; kc < 2; ++kc)
      wf3[nt][kc] = ldf4(wsh + W3P_OFF + (nt * 16 + lo) * 32 + kc * 16 + hi * 4);
  f16x4 xp3[4][4];                    // [mt][nt]
#pragma unroll
  for (int mt = 0; mt < 4; ++mt)
#pragma unroll
    for (int nt = 0; nt < 4; ++nt) {
      f32x4 acc = {bv3[nt], bv3[nt], bv3[nt], bv3[nt]};
#pragma unroll
      for (int kc = 0; kc < 2; ++kc)
        acc = MFMA16(a3[mt][kc], wf3[nt][kc], acc);
      xp3[mt][nt] = pk4(acc[0], acc[1], acc[2], acc[3]);
    }

  // ---- L3b: h = leaky(K~3 @ xp3) -> LDS (swizzled f16x4, R14's proven write) ----
#pragma unroll
  for (int nt = 0; nt < 4; ++nt)
#pragma unroll
    for (int kc = 0; kc < 4; ++kc)
      kb[nt][kc] = ldf4(kt + 3 * 4096 + (nt * 16 + lo) * 64 + kc * 16 + hi * 4);
#pragma unroll
  for (int ct = 0; ct < 4; ++ct)
#pragma unroll
    for (int rt = 0; rt < 4; ++rt) {
      f32x4 acc = {0.0f, 0.0f, 0.0f, 0.0f};
#pragma unroll
      for (int kc = 0; kc < 4; ++kc)
        acc = MFMA16(xp3[kc][rt], kb[ct][kc], acc);
      *(f16x4*)(P + swz(sx, ct * 16 + lo, rt * 16 + hi * 4)) =
          pk4(leaky(acc[0]), leaky(acc[1]), leaky(acc[2]), leaky(acc[3]));
    }

  __syncthreads();   // all 16 sample buffers staged before cross-wave dense reads

  // ---- phase D0: out80 = wm0 @ h.  A rows = 16 samples, 16-way K split ----
  f32x4 acc[5];
#pragma unroll
  for (int nt = 0; nt < 5; ++nt) { f32x4 z = {0.0f, 0.0f, 0.0f, 0.0f}; acc[nt] = z; }

  const _Float16* ap = &lds[lo][0];
#pragma unroll 2
  for (int it = 0; it < 8; ++it) {
    int kc = wv * 8 + it;                  // 128 kc chunks of 32 halves
    int row = kc >> 1, cc = (kc & 1) * 32 + hi * 8;
    f16x8 a = *(const f16x8*)(ap + swz(lo, row, cc));
    const _Float16* bp = wsh + (size_t)kc * 2560 + lo * 32 + hi * 8;
#pragma unroll
    for (int nt = 0; nt < 5; ++nt) {
      f16x8 b = *(const f16x8*)(bp + nt * 512);
      acc[nt] = MFMA32(a, b, acc[nt]);
    }
  }
  __syncthreads();                         // all dense reads of lds done

  // partials into reused LDS: part[wv][m<16][80]  (16 waves x 1280 floats = 80KB)
  float* scr = (float*)&lds[0][0];
#pragma unroll
  for (int nt = 0; nt < 5; ++nt)
#pragma unroll
    for (int r = 0; r < 4; ++r)
      scr[wv * 1280 + (hi * 4 + r) * 80 + nt * 16 + lo] = acc[nt][r];
  __syncthreads();

  // reduce across 16 waves + bias + leaky -> h1[16][80]
  float* h1 = scr + 20480;
  for (int e = tid; e < 1280; e += 1024) {
    int m = e / 80, n = e - m * 80;
    float v = bm0[n];
#pragma unroll
    for (int w = 0; w < 16; ++w) v += scr[w * 1280 + e];
    h1[e] = leaky(v);
  }
  __syncthreads();

  // ---- phase D1: out60 = wm1 @ h1 ----
  for (int e = tid; e < 960; e += 1024) {
    int m = e / 60, n = e - m * 60;
    float v = bm1[n];
    const float4* hr = (const float4*)(h1 + m * 80);
    const float4* wr = (const float4*)(wm1 + n * 80);
#pragma unroll
    for (int k2 = 0; k2 < 20; ++k2) {
      float4 hv = hr[k2], wv4 = wr[k2];
      v += hv.x * wv4.x + hv.y * wv4.y + hv.z * wv4.z + hv.w * wv4.w;
    }
    int s = smp0 + m;
    if (s < B) out[(size_t)s * 60 + n] = leaky(v);
  }
}

extern "C" void kernel_launch(void* const* d_in, const int* in_sizes, int n_in,
                              void* d_out, int out_size, void* d_ws, size_t ws_size,
                              hipStream_t stream) {
  const float* x   = (const float*)d_in[0];
  const float* w0  = (const float*)d_in[1];
  const float* b0  = (const float*)d_in[2];
  const float* s0  = (const float*)d_in[3];
  const float* w1  = (const float*)d_in[4];
  const float* b1  = (const float*)d_in[5];
  const float* s1  = (const float*)d_in[6];
  const float* w2  = (const float*)d_in[7];
  const float* b2  = (const float*)d_in[8];
  const float* s2  = (const float*)d_in[9];
  const float* w3  = (const float*)d_in[10];
  const float* b3  = (const float*)d_in[11];
  const float* s3  = (const float*)d_in[12];
  const float* wm0 = (const float*)d_in[13];
  const float* bm0 = (const float*)d_in[14];
  const float* wm1 = (const float*)d_in[15];
  const float* bm1 = (const float*)d_in[16];
  float* out = (float*)d_out;
  _Float16* wsh = (_Float16*)d_ws;

  int B = in_sizes[0] / 4096;

  prep_all<<<1282, 256, 0, stream>>>(s0, s1, s2, s3, w0, w1, w2, w3, wm0, wsh);
  fused<<<(B + 15) / 16, 1024, 0, stream>>>(x, b0, b1, b2, b3, wsh, bm0, wm1, bm1, out, B);
}

// Round 13
// 179.511 us; speedup vs baseline: 1.2928x; 1.2928x over previous
//
#include <hip/hip_runtime.h>

// R17 = R16 (verified register-resident gauss chain, zero LDS round-trips)
// + the two things R16 lost vs R14:
//   1. K~/w3 pre-tiled in prep so per-lane fragments are CONTIGUOUS:
//      ktt[row][hi*16+kc*4+j] -> 8 b128 loads/stage (was 16 b64);
//      w3t[row][hi*8+kc*4+j]  -> 4 b128 loads (was 8 b64).
//   2. single-buffer depth-1 prefetch: stage i+1's K~ loads issue right after
//      stage i's last use; an a-stage of MFMAs hides the L2 latency.
// No DS ops in the chain -> no fences. LDS only stages final h for the dense.

typedef _Float16 f16x8 __attribute__((ext_vector_type(8)));
typedef _Float16 f16x4 __attribute__((ext_vector_type(4)));
typedef __fp16   hf2   __attribute__((ext_vector_type(2)));
typedef float    f32x4 __attribute__((ext_vector_type(4)));

// ws layout (halves): wm0 tiled [128][80][32]; K~ tiled [4][64][64]; weights
#define KT_OFF    327680
#define W0P_OFF   344064               // [16][64], rows>=8 zero (K=32 B-frag layout)
#define W1P_OFF   345088               // [16][16], cols>=8 zero
#define W2P_OFF   345344               // [32][16]
#define W3P_OFF   345856               // [64][32] TILED [row][hi*8+kc*4+j]

__global__ void prep_all(const float* __restrict__ s0, const float* __restrict__ s1,
                         const float* __restrict__ s2, const float* __restrict__ s3,
                         const float* __restrict__ w0, const float* __restrict__ w1,
                         const float* __restrict__ w2, const float* __restrict__ w3,
                         const float* __restrict__ wm0, _Float16* __restrict__ base) {
  int bid = blockIdx.x, tid = threadIdx.x;
  if (bid < 1280) {
    // wm0 fp32 [80][4096] -> fp16 tiled [kc][n][32]
    int idx = bid * 256 + tid;
    int kc = idx / 2560, rem = idx % 2560;
    int n = rem >> 5, o = rem & 31;
    base[idx] = (_Float16)wm0[n * 4096 + kc * 32 + o];
  } else if (bid == 1280) {
    // K~ : L1-normalized gaussian rows, fp16, TILED [li][row][hi*16+kc*4+j]
    int li = tid >> 6, i = tid & 63;
    float sg = (li == 0) ? s0[0] : (li == 1) ? s1[0] : (li == 2) ? s2[0] : s3[0];
    float denom = 2.0f * sg * sg;
    float sum = 0.0f;
    for (int j = 0; j < 64; ++j) {
      float d = (float)(i - j);
      sum += expf(-(d * d) / denom);
    }
    float inv = 1.0f / fmaxf(sum, 1e-12f);
    for (int j = 0; j < 64; ++j) {
      float d = (float)(i - j);
      int p = ((j >> 2) & 3) * 16 + (j >> 4) * 4 + (j & 3);   // hi*16+kc*4+jj
      base[KT_OFF + (li * 64 + i) * 64 + p] = (_Float16)(expf(-(d * d) / denom) * inv);
    }
  } else {
    // small layer weights, zero-padded; w3 tiled [row][hi*8+kc*4+j]
    for (int r = tid; r < 3840; r += 256) {
      float v; int dst = r;
      if (r < 1024)      { int o = r >> 6, c = r & 63;             v = (o < 8) ? w0[o * 64 + c] : 0.0f; }
      else if (r < 1280) { int q = r - 1024; int o = q >> 4, c = q & 15; v = (c < 8) ? w1[o * 8 + c] : 0.0f; }
      else if (r < 1792) { int q = r - 1280; int o = q >> 4, c = q & 15; v = w2[o * 16 + c]; }
      else               { int q = r - 1792; int o = q >> 5, c = q & 31;
                           v = w3[o * 32 + c];
                           int p = ((c >> 2) & 3) * 8 + (c >> 4) * 4 + (c & 3);
                           dst = 1792 + o * 32 + p; }
      base[W0P_OFF + dst] = (_Float16)v;
    }
  }
}

__device__ __forceinline__ float leaky(float v) { return v > 0.0f ? v : 0.01f * v; }

__device__ __forceinline__ f16x4 pk4(float a, float b, float c, float d) {
  union { f16x4 v; hf2 p[2]; } u;
  u.p[0] = __builtin_amdgcn_cvt_pkrtz(a, b);
  u.p[1] = __builtin_amdgcn_cvt_pkrtz(c, d);
  return u.v;
}

// swizzled offset (halves) in an 8KB 64x64 fp16 buffer
__device__ __forceinline__ int swz(int sx, int row, int c) {
  return row * 64 + ((((c >> 3) ^ (row & 7) ^ sx) & 7) << 3) + (c & 7);
}

__device__ __forceinline__ f16x8 ldf(const _Float16* p) { return *(const f16x8*)p; }
__device__ __forceinline__ f16x4 ldf4(const _Float16* p) { return *(const f16x4*)p; }
__device__ __forceinline__ f16x4 lo4(f16x8 v) { return __builtin_shufflevector(v, v, 0, 1, 2, 3); }
__device__ __forceinline__ f16x4 hi4(f16x8 v) { return __builtin_shufflevector(v, v, 4, 5, 6, 7); }

#define MFMA16(A, B, C) __builtin_amdgcn_mfma_f32_16x16x16f16((A), (B), (C), 0, 0, 0)
#define MFMA32(A, B, C) __builtin_amdgcn_mfma_f32_16x16x32_f16((A), (B), (C), 0, 0, 0)

__global__ __launch_bounds__(1024, 4)
void fused(const float* __restrict__ x,
           const float* __restrict__ bb0, const float* __restrict__ bb1,
           const float* __restrict__ bb2, const float* __restrict__ bb3,
           const _Float16* __restrict__ wsh,
           const float* __restrict__ bm0, const float* __restrict__ wm1,
           const float* __restrict__ bm1, float* __restrict__ out, int B) {
  __shared__ _Float16 lds[16][4096];  // 128KB: h staging + dense scratch
  const int tid = threadIdx.x;
  const int wv = tid >> 6, lane = tid & 63;
  const int lo = lane & 15, hi = lane >> 4;
  const int smp0 = blockIdx.x * 16;
  int smp = smp0 + wv;  if (smp >= B) smp = B - 1;
  _Float16* P = lds[wv];
  const int sx = wv;
  const _Float16* kt = wsh + KT_OFF;

  float bv0 = (lo < 8) ? bb0[lo] : 0.0f;
  float bv1 = bb1[lo];
  float bv2[2] = {bb2[lo], bb2[16 + lo]};
  float bv3[4] = {bb3[lo], bb3[16 + lo], bb3[32 + lo], bb3[48 + lo]};

  // K~ fragment buffer (single, reloaded per layer): 8 x f16x8 = 32 VGPRs.
  // kb(nt,kc): kc0=lo4(kbu[2nt]) kc1=hi4(kbu[2nt]) kc2=lo4(kbu[2nt+1]) kc3=hi4(kbu[2nt+1])
  f16x8 kbu[8];
  const int ktrow = lo * 64 + hi * 16;     // (nt*16+lo)*64 + hi*16, nt added below
#define LOAD_KBU(li)                                                      \
  { _Pragma("unroll")                                                     \
    for (int nt = 0; nt < 4; ++nt) {                                      \
      const _Float16* p = kt + (li) * 4096 + nt * 1024 + ktrow;           \
      kbu[nt * 2]     = ldf(p);                                           \
      kbu[nt * 2 + 1] = ldf(p + 8);                                       \
    } }

  // ---- prefetch L0 weights + kt0 ----
  f16x8 wf0[2];
#pragma unroll
  for (int kc = 0; kc < 2; ++kc)
    wf0[kc] = ldf(wsh + W0P_OFF + lo * 64 + kc * 32 + hi * 8);
  LOAD_KBU(0);

  // ---- L0a: xp0 = x @ w0^T (A direct from global fp32 x, K=32) ----
  const float* xr = x + (size_t)smp * 4096;
  f16x4 xp0[4];                       // lane = xp0[mt*16+hi*4+q][lo]
#pragma unroll
  for (int mt = 0; mt < 4; ++mt) {
    f32x4 acc = {bv0, bv0, bv0, bv0};
#pragma unroll
    for (int kc = 0; kc < 2; ++kc) {
      const float4* p4 = (const float4*)(xr + (mt * 16 + lo) * 64 + kc * 32 + hi * 8);
      float4 v0 = p4[0], v1 = p4[1];
      union { f16x8 v; hf2 p[4]; } u;
      u.p[0] = __builtin_amdgcn_cvt_pkrtz(v0.x, v0.y);
      u.p[1] = __builtin_amdgcn_cvt_pkrtz(v0.z, v0.w);
      u.p[2] = __builtin_amdgcn_cvt_pkrtz(v1.x, v1.y);
      u.p[3] = __builtin_amdgcn_cvt_pkrtz(v1.z, v1.w);
      acc = MFMA32(u.v, wf0[kc], acc);
    }
    xp0[mt] = pk4(acc[0], acc[1], acc[2], acc[3]);
  }

  // prefetch w1 (used in L1a, after L0b)
  f16x4 wf1 = ldf4(wsh + W1P_OFF + lo * 16 + hi * 4);

  // ---- L0b: a1 = leaky(K~0 @ xp0) ----
  f16x4 a1[4];
#pragma unroll
  for (int nt = 0; nt < 4; ++nt) {
    f32x4 acc = {0.0f, 0.0f, 0.0f, 0.0f};
    acc = MFMA16(xp0[0], lo4(kbu[nt * 2]), acc);
    acc = MFMA16(xp0[1], hi4(kbu[nt * 2]), acc);
    acc = MFMA16(xp0[2], lo4(kbu[nt * 2 + 1]), acc);
    acc = MFMA16(xp0[3], hi4(kbu[nt * 2 + 1]), acc);
    a1[nt] = pk4(leaky(acc[0]), leaky(acc[1]), leaky(acc[2]), leaky(acc[3]));
  }

  LOAD_KBU(1);        // prefetch kt1; hidden under L1a

  // ---- L1a: xp1 = a1 @ w1^T ----
  f16x4 xp1[4];
#pragma unroll
  for (int mt = 0; mt < 4; ++mt) {
    f32x4 acc = {bv1, bv1, bv1, bv1};
    acc = MFMA16(a1[mt], wf1, acc);
    xp1[mt] = pk4(acc[0], acc[1], acc[2], acc[3]);
  }

  f16x4 wf2[2];       // prefetch w2 (used in L2a)
#pragma unroll
  for (int nt = 0; nt < 2; ++nt)
    wf2[nt] = ldf4(wsh + W2P_OFF + (nt * 16 + lo) * 16 + hi * 4);

  // ---- L1b: a2 = leaky(K~1 @ xp1) ----
  f16x4 a2[4];
#pragma unroll
  for (int nt = 0; nt < 4; ++nt) {
    f32x4 acc = {0.0f, 0.0f, 0.0f, 0.0f};
    acc = MFMA16(xp1[0], lo4(kbu[nt * 2]), acc);
    acc = MFMA16(xp1[1], hi4(kbu[nt * 2]), acc);
    acc = MFMA16(xp1[2], lo4(kbu[nt * 2 + 1]), acc);
    acc = MFMA16(xp1[3], hi4(kbu[nt * 2 + 1]), acc);
    a2[nt] = pk4(leaky(acc[0]), leaky(acc[1]), leaky(acc[2]), leaky(acc[3]));
  }

  LOAD_KBU(2);        // prefetch kt2; hidden under L2a

  // ---- L2a: xp2 = a2 @ w2^T (C'=32) ----
  f16x4 xp2[4][2];
#pragma unroll
  for (int mt = 0; mt < 4; ++mt)
#pragma unroll
    for (int nt = 0; nt < 2; ++nt) {
      f32x4 acc = {bv2[nt], bv2[nt], bv2[nt], bv2[nt]};
      acc = MFMA16(a2[mt], wf2[nt], acc);
      xp2[mt][nt] = pk4(acc[0], acc[1], acc[2], acc[3]);
    }

  // prefetch w3 tiled (used in L3a): 4 b128
  f16x8 wf3u[4];
#pragma unroll
  for (int nt = 0; nt < 4; ++nt)
    wf3u[nt] = ldf(wsh + W3P_OFF + (nt * 16 + lo) * 32 + hi * 8);

  // ---- L2b: a3 = leaky(K~2 @ xp2) ----
  f16x4 a3[4][2];
#pragma unroll
  for (int ct = 0; ct < 4; ++ct)
#pragma unroll
    for (int rt = 0; rt < 2; ++rt) {
      f32x4 acc = {0.0f, 0.0f, 0.0f, 0.0f};
      acc = MFMA16(xp2[0][rt], lo4(kbu[ct * 2]), acc);
      acc = MFMA16(xp2[1][rt], hi4(kbu[ct * 2]), acc);
      acc = MFMA16(xp2[2][rt], lo4(kbu[ct * 2 + 1]), acc);
      acc = MFMA16(xp2[3][rt], hi4(kbu[ct * 2 + 1]), acc);
      a3[ct][rt] = pk4(leaky(acc[0]), leaky(acc[1]), leaky(acc[2]), leaky(acc[3]));
    }

  LOAD_KBU(3);        // prefetch kt3; hidden under L3a

  // ---- L3a: xp3 = a3 @ w3^T (K=32 -> 2 kc, C'=64 -> 4 nt) ----
  f16x4 xp3[4][4];
#pragma unroll
  for (int mt = 0; mt < 4; ++mt)
#pragma unroll
    for (int nt = 0; nt < 4; ++nt) {
      f32x4 acc = {bv3[nt], bv3[nt], bv3[nt], bv3[nt]};
      acc = MFMA16(a3[mt][0], lo4(wf3u[nt]), acc);
      acc = MFMA16(a3[mt][1], hi4(wf3u[nt]), acc);
      xp3[mt][nt] = pk4(acc[0], acc[1], acc[2], acc[3]);
    }

  // ---- L3b: h = leaky(K~3 @ xp3) -> LDS (swizzled f16x4 writes) ----
#pragma unroll
  for (int ct = 0; ct < 4; ++ct)
#pragma unroll
    for (int rt = 0; rt < 4; ++rt) {
      f32x4 acc = {0.0f, 0.0f, 0.0f, 0.0f};
      acc = MFMA16(xp3[0][rt], lo4(kbu[ct * 2]), acc);
      acc = MFMA16(xp3[1][rt], hi4(kbu[ct * 2]), acc);
      acc = MFMA16(xp3[2][rt], lo4(kbu[ct * 2 + 1]), acc);
      acc = MFMA16(xp3[3][rt], hi4(kbu[ct * 2 + 1]), acc);
      *(f16x4*)(P + swz(sx, ct * 16 + lo, rt * 16 + hi * 4)) =
          pk4(leaky(acc[0]), leaky(acc[1]), leaky(acc[2]), leaky(acc[3]));
    }

  __syncthreads();   // all 16 sample buffers staged before cross-wave dense reads

  // ---- phase D0: out80 = wm0 @ h.  A rows = 16 samples, 16-way K split ----
  f32x4 acc[5];
#pragma unroll
  for (int nt = 0; nt < 5; ++nt) { f32x4 z = {0.0f, 0.0f, 0.0f, 0.0f}; acc[nt] = z; }

  const _Float16* ap = &lds[lo][0];
#pragma unroll 2
  for (int it = 0; it < 8; ++it) {
    int kc = wv * 8 + it;                  // 128 kc chunks of 32 halves
    int row = kc >> 1, cc = (kc & 1) * 32 + hi * 8;
    f16x8 a = *(const f16x8*)(ap + swz(lo, row, cc));
    const _Float16* bp = wsh + (size_t)kc * 2560 + lo * 32 + hi * 8;
#pragma unroll
    for (int nt = 0; nt < 5; ++nt) {
      f16x8 b = *(const f16x8*)(bp + nt * 512);
      acc[nt] = MFMA32(a, b, acc[nt]);
    }
  }
  __syncthreads();                         // all dense reads of lds done

  // partials into reused LDS: part[wv][m<16][80]
  float* scr = (float*)&lds[0][0];
#pragma unroll
  for (int nt = 0; nt < 5; ++nt)
#pragma unroll
    for (int r = 0; r < 4; ++r)
      scr[wv * 1280 + (hi * 4 + r) * 80 + nt * 16 + lo] = acc[nt][r];
  __syncthreads();

  // reduce across 16 waves + bias + leaky -> h1[16][80]
  float* h1 = scr + 20480;
  for (int e = tid; e < 1280; e += 1024) {
    int m = e / 80, n = e - m * 80;
    float v = bm0[n];
#pragma unroll
    for (int w = 0; w < 16; ++w) v += scr[w * 1280 + e];
    h1[e] = leaky(v);
  }
  __syncthreads();

  // ---- phase D1: out60 = wm1 @ h1 ----
  for (int e = tid; e < 960; e += 1024) {
    int m = e / 60, n = e - m * 60;
    float v = bm1[n];
    const float4* hr = (const float4*)(h1 + m * 80);
    const float4* wr = (const float4*)(wm1 + n * 80);
#pragma unroll
    for (int k2 = 0; k2 < 20; ++k2) {
      float4 hv = hr[k2], wv4 = wr[k2];
      v += hv.x * wv4.x + hv.y * wv4.y + hv.z * wv4.z + hv.w * wv4.w;
    }
    int s = smp0 + m;
    if (s < B) out[(size_t)s * 60 + n] = leaky(v);
  }
}

extern "C" void kernel_launch(void* const* d_in, const int* in_sizes, int n_in,
                              void* d_out, int out_size, void* d_ws, size_t ws_size,
                              hipStream_t stream) {
  const float* x   = (const float*)d_in[0];
  const float* w0  = (const float*)d_in[1];
  const float* b0  = (const float*)d_in[2];
  const float* s0  = (const float*)d_in[3];
  const float* w1  = (const float*)d_in[4];
  const float* b1  = (const float*)d_in[5];
  const float* s1  = (const float*)d_in[6];
  const float* w2  = (const float*)d_in[7];
  const float* b2  = (const float*)d_in[8];
  const float* s2  = (const float*)d_in[9];
  const float* w3  = (const float*)d_in[10];
  const float* b3  = (const float*)d_in[11];
  const float* s3  = (const float*)d_in[12];
  const float* wm0 = (const float*)d_in[13];
  const float* bm0 = (const float*)d_in[14];
  const float* wm1 = (const float*)d_in[15];
  const float* bm1 = (const float*)d_in[16];
  float* out = (float*)d_out;
  _Float16* wsh = (_Float16*)d_ws;

  int B = in_sizes[0] / 4096;

  prep_all<<<1282, 256, 0, stream>>>(s0, s1, s2, s3, w0, w1, w2, w3, wm0, wsh);
  fused<<<(B + 15) / 16, 1024, 0, stream>>>(x, b0, b1, b2, b3, wsh, bm0, wm1, bm1, out, B);
}